// Round 16
// baseline (94.372 us; speedup 1.0000x reference)
//
#include <hip/hip_runtime.h>

#define NUM_GRAPHS 512
#define N_NODES 100000
#define N_EDGES 1600000
#define D_NODE 128
#define D_EDGE 32
#define D_OUT 64

#define NBLK 512                 // count/place blocks
#define EPB (N_EDGES / NBLK)     // 3125 edges per block (exact)
#define NREM (EPB - 3072)        // 53 remainder edges
#define GCAP 5120                // per-graph id cap: deg mean 3125, sigma ~228 -> 8.7 sigma

// ---------------- kernel 1: count per-(block,graph) + materialize eg ------------------
__global__ __launch_bounds__(512) void count_kernel(const int* __restrict__ col,
                                                    const int* __restrict__ batch,
                                                    int* __restrict__ eg,
                                                    int* __restrict__ cntT) {
    __shared__ int cur[NUM_GRAPHS];
    const int t = threadIdx.x, b = blockIdx.x;
    cur[t] = 0;
    __syncthreads();
    const int base = b * EPB;

    int c[6], gg[6];
    #pragma unroll
    for (int r = 0; r < 6; ++r) c[r] = col[base + r * 512 + t];      // 6 coalesced loads in flight
    #pragma unroll
    for (int r = 0; r < 6; ++r) gg[r] = batch[c[r]];                 // 6 independent gathers
    #pragma unroll
    for (int r = 0; r < 6; ++r) {
        eg[base + r * 512 + t] = gg[r];                              // coalesced
        atomicAdd(&cur[gg[r]], 1);
    }
    if (t < NREM) {                                                  // 53 remainder
        const int g = batch[col[base + 3072 + t]];
        eg[base + 3072 + t] = g;
        atomicAdd(&cur[g], 1);
    }
    __syncthreads();
    cntT[t * NBLK + b] = cur[t];                                     // [g][b], scattered -> L2
}

// ---------------- kernel 2: per-graph scan over blocks (wave-shuffle, 1 barrier) ------
__global__ __launch_bounds__(512) void scan_kernel(const int* __restrict__ cntT,
                                                   int* __restrict__ pos,
                                                   int* __restrict__ totals) {
    const int g = blockIdx.x, t = threadIdx.x;
    const int n = cntT[g * NBLK + t];                                // coalesced
    const int lane = t & 63, w = t >> 6;
    __shared__ int wtot[8], wbase[8];
    int v = n;
    #pragma unroll
    for (int off = 1; off < 64; off <<= 1) {
        const int u = __shfl_up(v, off, 64);
        if (lane >= off) v += u;
    }
    if (lane == 63) wtot[w] = v;
    __syncthreads();
    if (t == 0) {
        int s = 0;
        #pragma unroll
        for (int i = 0; i < 8; ++i) { wbase[i] = s; s += wtot[i]; }
    }
    __syncthreads();
    pos[t * NUM_GRAPHS + g] = g * GCAP + wbase[w] + v - n;           // [b][g], scattered -> L2
    if (t == 511) totals[g] = wbase[7] + v;
}

// ---------------- kernel 3: place edge ids into dense per-graph rows ------------------
__global__ __launch_bounds__(512) void place_kernel(const int* __restrict__ eg,
                                                    const int* __restrict__ pos,
                                                    int* __restrict__ bucket) {
    __shared__ int cur[NUM_GRAPHS];
    const int t = threadIdx.x, b = blockIdx.x;
    cur[t] = pos[b * NUM_GRAPHS + t];                                // coalesced
    __syncthreads();
    const int base = b * EPB;
    #pragma unroll
    for (int r = 0; r < 6; ++r) {
        const int i = r * 512 + t;
        const int g = eg[base + i];                                  // coalesced
        const int s = atomicAdd(&cur[g], 1);
        bucket[s] = base + i;                                        // scattered 4B -> L2 (10.5MB fits)
    }
    if (t < NREM) {
        const int i = 3072 + t;
        const int g = eg[base + i];
        bucket[atomicAdd(&cur[g], 1)] = base + i;
    }
}

// ---------------- kernel 4: fused INTERLEAVED node-stream + edge-gather + tiny GEMM ---
// One merged loop: each iteration issues 4 edge-gather chains (expensive, ~4.4 TB/s
// random) AND 1 coalesced node float4 load (cheap streaming) -> the controller fills
// gather-idle DRAM slots with the node stream, hiding the ~10us node phase.
__global__ __launch_bounds__(1024) void fused_kernel(const float* __restrict__ x,
                                                     const int* __restrict__ batch,
                                                     const float* __restrict__ edge_attr,
                                                     const int* __restrict__ totals,
                                                     const int* __restrict__ bucket,
                                                     const float* __restrict__ W,
                                                     const float* __restrict__ bias,
                                                     float* __restrict__ out) {
    const int g = blockIdx.x;
    const int t = threadIdx.x;
    __shared__ float4 red[1024];
    __shared__ float4 red2[64];
    __shared__ __align__(16) float feat[D_NODE + D_EDGE];

    const int ntot = min(totals[g], GCAP);
    const int* brow = bucket + g * GCAP;

    // node range via binary search (batch sorted)
    int l = 0, r = N_NODES;
    while (l < r) { int m = (l + r) >> 1; if (batch[m] < g) l = m + 1; else r = m; }
    const int lo = l;
    r = N_NODES;
    while (l < r) { int m = (l + r) >> 1; if (batch[m] < g + 1) l = m + 1; else r = m; }
    const int hi = l;

    // merged loop: node (d4 = t&31 col, rr = t>>5 row 0..31, stride 32) interleaved
    // with edge (slot0 = t>>3, dq = t&7, 4 chains, stride 512)
    const float4* x4 = reinterpret_cast<const float4*>(x);
    const float4* ea4 = reinterpret_cast<const float4*>(edge_attr);
    const int d4 = t & 31, rr = t >> 5;
    const int slot0 = t >> 3, dq = t & 7;

    const int nIterN = (hi - lo + 31) >> 5;                  // node iterations
    const int nIterE = (ntot + 511) >> 9;                    // edge iterations
    const int nIter = max(nIterN, nIterE);

    float4 an = make_float4(0.f, 0.f, 0.f, 0.f);             // node accumulator
    float4 a0 = make_float4(0.f, 0.f, 0.f, 0.f);             // edge accumulators
    float4 a1 = make_float4(0.f, 0.f, 0.f, 0.f);
    float4 a2 = make_float4(0.f, 0.f, 0.f, 0.f);
    float4 a3 = make_float4(0.f, 0.f, 0.f, 0.f);

    for (int it = 0; it < nIter; ++it) {
        // edge slots for this iteration
        const int base = it << 9;
        const int s0 = base + slot0, s1 = s0 + 128, s2 = s0 + 256, s3 = s0 + 384;
        const int id0 = (s0 < ntot) ? brow[s0] : -1;         // 8-lane broadcast
        const int id1 = (s1 < ntot) ? brow[s1] : -1;
        const int id2 = (s2 < ntot) ? brow[s2] : -1;
        const int id3 = (s3 < ntot) ? brow[s3] : -1;
        // node row for this iteration (issued alongside the gathers)
        const int ni = lo + (it << 5) + rr;
        if (ni < hi) {
            const float4 v = x4[(size_t)ni * 32 + d4];
            an.x += v.x; an.y += v.y; an.z += v.z; an.w += v.w;
        }
        if (id0 >= 0) { const float4 u = ea4[(size_t)id0 * 8 + dq]; a0.x += u.x; a0.y += u.y; a0.z += u.z; a0.w += u.w; }
        if (id1 >= 0) { const float4 u = ea4[(size_t)id1 * 8 + dq]; a1.x += u.x; a1.y += u.y; a1.z += u.z; a1.w += u.w; }
        if (id2 >= 0) { const float4 u = ea4[(size_t)id2 * 8 + dq]; a2.x += u.x; a2.y += u.y; a2.z += u.z; a2.w += u.w; }
        if (id3 >= 0) { const float4 u = ea4[(size_t)id3 * 8 + dq]; a3.x += u.x; a3.y += u.y; a3.z += u.z; a3.w += u.w; }
    }

    // node reduction: red[t] = an (layout rr*32 + d4)
    red[t] = an;
    __syncthreads();
    if (t < 32) {
        float4 s = red[t];
        #pragma unroll
        for (int p = 1; p < 32; ++p) {
            const float4 u = red[p * 32 + t];
            s.x += u.x; s.y += u.y; s.z += u.z; s.w += u.w;
        }
        reinterpret_cast<float4*>(feat)[t] = s;              // feat[0..127]
    }
    __syncthreads();

    // edge reduction
    a0.x += a1.x + a2.x + a3.x;
    a0.y += a1.y + a2.y + a3.y;
    a0.z += a1.z + a2.z + a3.z;
    a0.w += a1.w + a2.w + a3.w;
    red[t] = a0;                                             // red[slot0*8 + dq]
    __syncthreads();
    if (t < 64) {                                            // part = t>>3, dq2 = t&7
        const int part = t >> 3, dq2 = t & 7;
        float4 s = make_float4(0.f, 0.f, 0.f, 0.f);
        #pragma unroll
        for (int k = 0; k < 16; ++k) {
            const float4 u = red[(part * 16 + k) * 8 + dq2];
            s.x += u.x; s.y += u.y; s.z += u.z; s.w += u.w;
        }
        red2[t] = s;
    }
    __syncthreads();
    if (t < 8) {
        float4 s = red2[t];
        #pragma unroll
        for (int k = 1; k < 8; ++k) {
            const float4 u = red2[k * 8 + t];
            s.x += u.x; s.y += u.y; s.z += u.z; s.w += u.w;
        }
        reinterpret_cast<float4*>(feat + D_NODE)[t] = s;     // feat[128..159]
    }
    __syncthreads();

    // gemm: out[g][t], t < 64
    if (t < D_OUT) {
        float o = bias[t];
        #pragma unroll 8
        for (int k = 0; k < D_NODE + D_EDGE; ++k)
            o += feat[k] * W[k * D_OUT + t];                 // W (41 KB) L2/L3-hot
        out[g * D_OUT + t] = o;
    }
}

extern "C" void kernel_launch(void* const* d_in, const int* in_sizes, int n_in,
                              void* d_out, int out_size, void* d_ws, size_t ws_size,
                              hipStream_t stream) {
    const float* x          = (const float*)d_in[0];
    const int*   edge_index = (const int*)d_in[1];
    const float* edge_attr  = (const float*)d_in[2];
    // d_in[3] = u, unused by the reference output
    const int*   batch      = (const int*)d_in[4];
    const float* W          = (const float*)d_in[5];
    const float* b          = (const float*)d_in[6];
    float* out = (float*)d_out;

    const int* col = edge_index + N_EDGES;   // row 1 of edge_index

    // workspace layout (~18.9 MB)
    int* eg     = (int*)d_ws;                                  // 6.4 MB
    int* cntT   = eg + N_EDGES;                                // [g][b] 1 MB
    int* pos    = cntT + NUM_GRAPHS * NBLK;                    // [b][g] 1 MB
    int* totals = pos + NBLK * NUM_GRAPHS;                     // 512 ints
    int* bucket = totals + NUM_GRAPHS;                         // 512*5120 = 10.5 MB

    count_kernel<<<NBLK, 512, 0, stream>>>(col, batch, eg, cntT);
    scan_kernel<<<NUM_GRAPHS, 512, 0, stream>>>(cntT, pos, totals);
    place_kernel<<<NBLK, 512, 0, stream>>>(eg, pos, bucket);
    fused_kernel<<<NUM_GRAPHS, 1024, 0, stream>>>(x, batch, edge_attr, totals, bucket, W, b, out);
}

// Round 17
// 81.640 us; speedup vs baseline: 1.1560x; 1.1560x over previous
//
#include <hip/hip_runtime.h>

#define NUM_GRAPHS 512
#define N_NODES 100000
#define N_EDGES 1600000
#define D_NODE 128
#define D_EDGE 32
#define D_OUT 64

#define NBLK 512                 // count/place blocks
#define EPB (N_EDGES / NBLK)     // 3125 edges per block (exact)
#define NREM (EPB - 3072)        // 53 remainder edges
#define GCAP 5120                // per-graph id cap: deg mean 3125, sigma ~228 -> 8.7 sigma

// ---------------- kernel 1: count per-(block,graph) histogram (no eg materialized) ----
__global__ __launch_bounds__(512) void count_kernel(const int* __restrict__ col,
                                                    const int* __restrict__ batch,
                                                    int* __restrict__ cntT) {
    __shared__ int cur[NUM_GRAPHS];
    const int t = threadIdx.x, b = blockIdx.x;
    cur[t] = 0;
    __syncthreads();
    const int base = b * EPB;

    int c[6], gg[6];
    #pragma unroll
    for (int r = 0; r < 6; ++r) c[r] = col[base + r * 512 + t];      // 6 coalesced loads in flight
    #pragma unroll
    for (int r = 0; r < 6; ++r) gg[r] = batch[c[r]];                 // 6 independent gathers
    #pragma unroll
    for (int r = 0; r < 6; ++r) atomicAdd(&cur[gg[r]], 1);
    if (t < NREM) {                                                  // 53 remainder
        const int g = batch[col[base + 3072 + t]];
        atomicAdd(&cur[g], 1);
    }
    __syncthreads();
    cntT[t * NBLK + b] = cur[t];                                     // [g][b], scattered -> L2
}

// ---------------- kernel 2: per-graph scan over blocks (wave-shuffle, 1 barrier) ------
__global__ __launch_bounds__(512) void scan_kernel(const int* __restrict__ cntT,
                                                   int* __restrict__ pos,
                                                   int* __restrict__ totals) {
    const int g = blockIdx.x, t = threadIdx.x;
    const int n = cntT[g * NBLK + t];                                // coalesced
    const int lane = t & 63, w = t >> 6;
    __shared__ int wtot[8], wbase[8];
    int v = n;
    #pragma unroll
    for (int off = 1; off < 64; off <<= 1) {
        const int u = __shfl_up(v, off, 64);
        if (lane >= off) v += u;
    }
    if (lane == 63) wtot[w] = v;
    __syncthreads();
    if (t == 0) {
        int s = 0;
        #pragma unroll
        for (int i = 0; i < 8; ++i) { wbase[i] = s; s += wtot[i]; }
    }
    __syncthreads();
    pos[t * NUM_GRAPHS + g] = g * GCAP + wbase[w] + v - n;           // [b][g], scattered -> L2
    if (t == 511) totals[g] = wbase[7] + v;
}

// ---------------- kernel 3: place edge ids (re-gathers g; no eg read) -----------------
__global__ __launch_bounds__(512) void place_kernel(const int* __restrict__ col,
                                                    const int* __restrict__ batch,
                                                    const int* __restrict__ pos,
                                                    int* __restrict__ bucket) {
    __shared__ int cur[NUM_GRAPHS];
    const int t = threadIdx.x, b = blockIdx.x;
    cur[t] = pos[b * NUM_GRAPHS + t];                                // coalesced
    const int base = b * EPB;
    int c[6], gg[6];
    #pragma unroll
    for (int r = 0; r < 6; ++r) c[r] = col[base + r * 512 + t];      // col re-read: L2/L3-warm
    #pragma unroll
    for (int r = 0; r < 6; ++r) gg[r] = batch[c[r]];                 // 6 independent gathers
    __syncthreads();                                                 // cur ready
    #pragma unroll
    for (int r = 0; r < 6; ++r) {
        const int s = atomicAdd(&cur[gg[r]], 1);
        bucket[s] = base + r * 512 + t;                              // scattered 4B -> L2
    }
    if (t < NREM) {
        const int g = batch[col[base + 3072 + t]];
        bucket[atomicAdd(&cur[g], 1)] = base + 3072 + t;
    }
}

// ---------------- kernel 4: fused node-sum + edge gather-sum + tiny GEMM (R11) --------
__global__ __launch_bounds__(1024) void fused_kernel(const float* __restrict__ x,
                                                     const int* __restrict__ batch,
                                                     const float* __restrict__ edge_attr,
                                                     const int* __restrict__ totals,
                                                     const int* __restrict__ bucket,
                                                     const float* __restrict__ W,
                                                     const float* __restrict__ bias,
                                                     float* __restrict__ out) {
    const int g = blockIdx.x;
    const int t = threadIdx.x;
    __shared__ float4 red[1024];
    __shared__ float4 red2[64];
    __shared__ __align__(16) float feat[D_NODE + D_EDGE];

    const int ntot = min(totals[g], GCAP);
    const int* brow = bucket + g * GCAP;

    // node range via binary search (batch sorted)
    int l = 0, r = N_NODES;
    while (l < r) { int m = (l + r) >> 1; if (batch[m] < g) l = m + 1; else r = m; }
    const int lo = l;
    r = N_NODES;
    while (l < r) { int m = (l + r) >> 1; if (batch[m] < g + 1) l = m + 1; else r = m; }
    const int hi = l;

    // node phase: d4 = t&31 float4 col, rr = t>>5 row phase (0..31)
    const float4* x4 = reinterpret_cast<const float4*>(x);
    const int d4 = t & 31, rr = t >> 5;
    float4 a = make_float4(0.f, 0.f, 0.f, 0.f);
    for (int i = lo + rr; i < hi; i += 32) {
        const float4 v = x4[(size_t)i * 32 + d4];
        a.x += v.x; a.y += v.y; a.z += v.z; a.w += v.w;
    }
    red[t] = a;
    __syncthreads();
    if (t < 32) {                                // node reduce -> feat[0..127]
        float4 s = red[t];
        #pragma unroll
        for (int p = 1; p < 32; ++p) {
            const float4 u = red[p * 32 + t];
            s.x += u.x; s.y += u.y; s.z += u.z; s.w += u.w;
        }
        reinterpret_cast<float4*>(feat)[t] = s;
    }
    __syncthreads();                             // red free for reuse

    // edge phase: slot0 = t>>3 (0..127), dq = t&7; 4 independent id->attr gather chains
    const float4* ea4 = reinterpret_cast<const float4*>(edge_attr);
    const int slot0 = t >> 3, dq = t & 7;
    float4 a0 = make_float4(0.f, 0.f, 0.f, 0.f);
    float4 a1 = make_float4(0.f, 0.f, 0.f, 0.f);
    float4 a2 = make_float4(0.f, 0.f, 0.f, 0.f);
    float4 a3 = make_float4(0.f, 0.f, 0.f, 0.f);
    for (int base = 0; base < ntot; base += 512) {
        const int s0 = base + slot0, s1 = s0 + 128, s2 = s0 + 256, s3 = s0 + 384;
        const int id0 = (s0 < ntot) ? brow[s0] : -1;   // 8-lane broadcast, L2-warm
        const int id1 = (s1 < ntot) ? brow[s1] : -1;
        const int id2 = (s2 < ntot) ? brow[s2] : -1;
        const int id3 = (s3 < ntot) ? brow[s3] : -1;
        if (id0 >= 0) { const float4 u = ea4[(size_t)id0 * 8 + dq]; a0.x += u.x; a0.y += u.y; a0.z += u.z; a0.w += u.w; }
        if (id1 >= 0) { const float4 u = ea4[(size_t)id1 * 8 + dq]; a1.x += u.x; a1.y += u.y; a1.z += u.z; a1.w += u.w; }
        if (id2 >= 0) { const float4 u = ea4[(size_t)id2 * 8 + dq]; a2.x += u.x; a2.y += u.y; a2.z += u.z; a2.w += u.w; }
        if (id3 >= 0) { const float4 u = ea4[(size_t)id3 * 8 + dq]; a3.x += u.x; a3.y += u.y; a3.z += u.z; a3.w += u.w; }
    }
    a0.x += a1.x + a2.x + a3.x;
    a0.y += a1.y + a2.y + a3.y;
    a0.z += a1.z + a2.z + a3.z;
    a0.w += a1.w + a2.w + a3.w;
    red[t] = a0;                                 // red[slot0*8 + dq]
    __syncthreads();
    if (t < 64) {                                // part = t>>3 (0..7), dq2 = t&7
        const int part = t >> 3, dq2 = t & 7;
        float4 s = make_float4(0.f, 0.f, 0.f, 0.f);
        #pragma unroll
        for (int k = 0; k < 16; ++k) {
            const float4 u = red[(part * 16 + k) * 8 + dq2];
            s.x += u.x; s.y += u.y; s.z += u.z; s.w += u.w;
        }
        red2[t] = s;
    }
    __syncthreads();
    if (t < 8) {
        float4 s = red2[t];
        #pragma unroll
        for (int k = 1; k < 8; ++k) {
            const float4 u = red2[k * 8 + t];
            s.x += u.x; s.y += u.y; s.z += u.z; s.w += u.w;
        }
        reinterpret_cast<float4*>(feat + D_NODE)[t] = s;   // feat[128..159]
    }
    __syncthreads();

    // gemm: out[g][t], t < 64
    if (t < D_OUT) {
        float o = bias[t];
        #pragma unroll 8
        for (int k = 0; k < D_NODE + D_EDGE; ++k)
            o += feat[k] * W[k * D_OUT + t];     // W (41 KB) L2/L3-hot, coalesced per k
        out[g * D_OUT + t] = o;
    }
}

extern "C" void kernel_launch(void* const* d_in, const int* in_sizes, int n_in,
                              void* d_out, int out_size, void* d_ws, size_t ws_size,
                              hipStream_t stream) {
    const float* x          = (const float*)d_in[0];
    const int*   edge_index = (const int*)d_in[1];
    const float* edge_attr  = (const float*)d_in[2];
    // d_in[3] = u, unused by the reference output
    const int*   batch      = (const int*)d_in[4];
    const float* W          = (const float*)d_in[5];
    const float* b          = (const float*)d_in[6];
    float* out = (float*)d_out;

    const int* col = edge_index + N_EDGES;   // row 1 of edge_index

    // workspace layout (~12.5 MB)
    int* cntT   = (int*)d_ws;                                  // [g][b] 1 MB
    int* pos    = cntT + NUM_GRAPHS * NBLK;                    // [b][g] 1 MB
    int* totals = pos + NBLK * NUM_GRAPHS;                     // 512 ints
    int* bucket = totals + NUM_GRAPHS;                         // 512*5120 = 10.5 MB

    count_kernel<<<NBLK, 512, 0, stream>>>(col, batch, cntT);
    scan_kernel<<<NUM_GRAPHS, 512, 0, stream>>>(cntT, pos, totals);
    place_kernel<<<NBLK, 512, 0, stream>>>(col, batch, pos, bucket);
    fused_kernel<<<NUM_GRAPHS, 1024, 0, stream>>>(x, batch, edge_attr, totals, bucket, W, b, out);
}